// Round 12
// baseline (175.699 us; speedup 1.0000x reference)
//
#include <hip/hip_runtime.h>
#include <stdint.h>

// WindowAttention B=8 H=W=256 C=96 ws=8 heads=4 hd=24 — MFMA, mixed fp8/f16.
// R12 = R11 (2 windows/block, prepacked weights, no-max softmax) +
//   q/k staged as fp8 e4m3 (S via mfma_f32_16x16x32_fp8_fp8)
//   -> LDS 51200 B -> 3 blocks/CU (12 waves, +50% TLP)
//   + biases folded into MFMA C-init; o2 f32 overlays whole window region.

typedef _Float16 f16;
typedef f16 f16x8 __attribute__((ext_vector_type(8)));
typedef f16 f16x4 __attribute__((ext_vector_type(4)));
typedef __fp16 hf2 __attribute__((ext_vector_type(2)));
typedef float f32x4 __attribute__((ext_vector_type(4)));

#define MFMA_K32  __builtin_amdgcn_mfma_f32_16x16x32_f16       // A/B f16x8
#define MFMA_FP8  __builtin_amdgcn_mfma_f32_16x16x32_fp8_fp8   // A/B long (8 fp8)

#define KE 0.29448890f  // 24^-0.5 * log2(e), folded into Q weights+bias

// vt rows 64 f16 wide, XOR-swizzled 16-B octets: conflict-free b128 reads
__device__ __forceinline__ int vtidx(int row, int col) { return row*64 + (col ^ ((row & 7) << 3)); }

__device__ __forceinline__ f16x4 pk4(float a, float b, float c, float d) {
    union { f16x4 v; hf2 h[2]; } u;
    u.h[0] = __builtin_amdgcn_cvt_pkrtz(a, b);
    u.h[1] = __builtin_amdgcn_cvt_pkrtz(c, d);
    return u.v;
}

__device__ __forceinline__ int pk_fp8x4(float a, float b, float c, float d) {
    int v = __builtin_amdgcn_cvt_pk_fp8_f32(a, b, 0, false);   // low 16 bits
    v = __builtin_amdgcn_cvt_pk_fp8_f32(c, d, v, true);        // high 16 bits
    return v;
}

// Prepack weights into per-wave MFMA fragment order (q-rows pre-scaled by KE);
// scaled q-bias (float[96]) at f16 offset 36864.
__global__ void prep_weights(const float* __restrict__ qkv_w,
                             const float* __restrict__ proj_w,
                             const float* __restrict__ qkv_b,
                             f16* __restrict__ ws) {
    const int u = blockIdx.x * 256 + threadIdx.x;
    if (u < 3456) {
        const int lane = u & 63, unit = u >> 6;
        const int n = unit / 3, kk = unit - 3*n;
        const int lr = lane & 15, lg = lane >> 4;
        const float sc = (n < 6) ? KE : 1.0f;
        const float* s = qkv_w + (16*n + lr)*96 + kk*32 + lg*8;
        f16x8 v;
        #pragma unroll
        for (int e = 0; e < 8; ++e) v[e] = (f16)(s[e] * sc);
        *(f16x8*)(ws + (size_t)u*8) = v;
    } else if (u < 4608) {
        const int uu = u - 3456;
        const int lane = uu & 63, unit = uu >> 6;
        const int n = unit / 3, kk = unit - 3*n;
        const int lr = lane & 15, lg = lane >> 4;
        const float* s = proj_w + (16*n + lr)*96 + kk*32 + lg*8;
        f16x8 v;
        #pragma unroll
        for (int e = 0; e < 8; ++e) v[e] = (f16)s[e];
        *(f16x8*)(ws + 27648 + (size_t)uu*8) = v;
    } else if (u < 4704) {
        const int j = u - 4608;
        ((float*)(ws + 36864))[j] = qkv_b[j] * KE;
    }
}

__global__ __launch_bounds__(256, 3) void winattn(
    const float* __restrict__ x,
    const f16*   __restrict__ wsq,     // prepacked qkv_w fragments (+ scaled q-bias)
    const float* __restrict__ qkv_b,   // [288] (k/v bias raw)
    const f16*   __restrict__ wsp,     // prepacked proj_w fragments
    const float* __restrict__ proj_b,  // [96]
    float* __restrict__ out)
{
    // Per-window region (25600 B): q8[64x104B] | k8[64x104B] | vt f16[96x64]
    //   After B2: O f16 [64][104] overlays q8+k8 (13312 B).
    //   After B4: o2 f32 [64][100] overlays the whole region (25600 B).
    __shared__ __align__(16) char smem[51200];
    uint8_t* q8A = (uint8_t*)smem;
    uint8_t* k8A = q8A + 6656;
    f16* vtA = (f16*)(smem + 13312);
    f16* ObA = (f16*)smem;
    float* o2A = (float*)smem;
    uint8_t* q8B = (uint8_t*)(smem + 25600);
    uint8_t* k8B = q8B + 6656;
    f16* vtB = (f16*)(smem + 25600 + 13312);
    f16* ObB = (f16*)(smem + 25600);
    float* o2B = (float*)(smem + 25600);

    const int tid = threadIdx.x;
    const int wid = blockIdx.x * 2;            // window A; B = wid+1 (same row)
    const int bb = wid >> 10, wh = (wid >> 5) & 31, ww = wid & 31;
    const size_t win_baseA = ((size_t)(bb*256 + wh*8)*256 + (size_t)(ww*8)) * 96;

    const int lane = tid & 63, w = tid >> 6;
    const int lr = lane & 15, lg = lane >> 4;
    const int t = 16*w + lr;                   // this lane's token (phases 1,3)
    const size_t tok_offA = win_baseA + (size_t)(((t>>3)<<8) + (t&7))*96;
    const size_t tok_offB = tok_offA + 768;    // +8 pixels * 96 ch

    const f16* wqL = wsq + lane*8;             // per-lane fragment base (qkv)
    const f16* wpL = wsp + lane*8;             // per-lane fragment base (proj)
    const float* qbs = (const float*)(wsq + 36864);  // scaled q-bias

    // ---- phase 1: x fragments for both windows (12 dwordx4 loads in flight)
    f16x8 axA[3], axB[3];
    #pragma unroll
    for (int kk = 0; kk < 3; ++kk) {
        const float* xpA = x + tok_offA + kk*32 + lg*8;
        const float* xpB = x + tok_offB + kk*32 + lg*8;
        const float4 a0 = *(const float4*)xpA;
        const float4 a1 = *(const float4*)(xpA + 4);
        const float4 b0 = *(const float4*)xpB;
        const float4 b1 = *(const float4*)(xpB + 4);
        union { f16x8 v; f16x4 q[2]; } ua, ub;
        ua.q[0] = pk4(a0.x, a0.y, a0.z, a0.w);
        ua.q[1] = pk4(a1.x, a1.y, a1.z, a1.w);
        ub.q[0] = pk4(b0.x, b0.y, b0.z, b0.w);
        ub.q[1] = pk4(b1.x, b1.y, b1.z, b1.w);
        axA[kk] = ua.v;
        axB[kk] = ub.v;
    }
    // permuted v^T column for this lane's token t (u_k with perm(u_k) = t)
    const int vcol = (w>>1)*32 + (lr>>2)*8 + (w&1)*4 + (lr&3);

    // ======== Q group (n=0..5): weights loaded ONCE; bias as C-init; fp8 epilogue
    {
        f16x8 wf[6][3];
        #pragma unroll
        for (int nn = 0; nn < 6; ++nn)
            #pragma unroll
            for (int kk = 0; kk < 3; ++kk)
                wf[nn][kk] = *(const f16x8*)(wqL + (nn*3 + kk)*512);
        #pragma unroll
        for (int nn = 0; nn < 6; ++nn) {
            const int j0 = 16*nn + 4*lg;
            const float4 b4 = *(const float4*)(qbs + j0);      // scaled q-bias
            f32x4 accA = {b4.x, b4.y, b4.z, b4.w};
            f32x4 accB = accA;
            #pragma unroll
            for (int kk = 0; kk < 3; ++kk) {
                accA = MFMA_K32(wf[nn][kk], axA[kk], accA, 0,0,0);
                accB = MFMA_K32(wf[nn][kk], axB[kk], accB, 0,0,0);
            }
            *(int*)(q8A + t*104 + j0) = pk_fp8x4(accA[0], accA[1], accA[2], accA[3]);
            *(int*)(q8B + t*104 + j0) = pk_fp8x4(accB[0], accB[1], accB[2], accB[3]);
        }
    }
    // ======== K group (n=6..11): fp8 epilogue
    {
        f16x8 wf[6][3];
        #pragma unroll
        for (int nn = 0; nn < 6; ++nn)
            #pragma unroll
            for (int kk = 0; kk < 3; ++kk)
                wf[nn][kk] = *(const f16x8*)(wqL + ((nn+6)*3 + kk)*512);
        #pragma unroll
        for (int nn = 0; nn < 6; ++nn) {
            const int j0 = 16*nn + 4*lg;
            const float4 b4 = *(const float4*)(qkv_b + 96 + j0);
            f32x4 accA = {b4.x, b4.y, b4.z, b4.w};
            f32x4 accB = accA;
            #pragma unroll
            for (int kk = 0; kk < 3; ++kk) {
                accA = MFMA_K32(wf[nn][kk], axA[kk], accA, 0,0,0);
                accB = MFMA_K32(wf[nn][kk], axB[kk], accB, 0,0,0);
            }
            *(int*)(k8A + t*104 + j0) = pk_fp8x4(accA[0], accA[1], accA[2], accA[3]);
            *(int*)(k8B + t*104 + j0) = pk_fp8x4(accB[0], accB[1], accB[2], accB[3]);
        }
    }
    // ======== V group (n=12..17) -> vt (f16) permuted columns
    {
        f16x8 wf[6][3];
        #pragma unroll
        for (int nn = 0; nn < 6; ++nn)
            #pragma unroll
            for (int kk = 0; kk < 3; ++kk)
                wf[nn][kk] = *(const f16x8*)(wqL + ((nn+12)*3 + kk)*512);
        #pragma unroll
        for (int nn = 0; nn < 6; ++nn) {
            const int j0 = 16*nn + 4*lg;
            const float4 b4 = *(const float4*)(qkv_b + 192 + j0);
            f32x4 accA = {b4.x, b4.y, b4.z, b4.w};
            f32x4 accB = accA;
            #pragma unroll
            for (int kk = 0; kk < 3; ++kk) {
                accA = MFMA_K32(wf[nn][kk], axA[kk], accA, 0,0,0);
                accB = MFMA_K32(wf[nn][kk], axB[kk], accB, 0,0,0);
            }
            const int hv = (unsigned)j0 / 24u, d0 = j0 - 24*hv;
            vtA[vtidx(hv*24 + d0+0, vcol)] = (f16)accA[0];
            vtA[vtidx(hv*24 + d0+1, vcol)] = (f16)accA[1];
            vtA[vtidx(hv*24 + d0+2, vcol)] = (f16)accA[2];
            vtA[vtidx(hv*24 + d0+3, vcol)] = (f16)accA[3];
            vtB[vtidx(hv*24 + d0+0, vcol)] = (f16)accB[0];
            vtB[vtidx(hv*24 + d0+1, vcol)] = (f16)accB[1];
            vtB[vtidx(hv*24 + d0+2, vcol)] = (f16)accB[2];
            vtB[vtidx(hv*24 + d0+3, vcol)] = (f16)accB[3];
        }
    }
    __syncthreads();   // B1: q8/k8/vt staged for both windows

    // ---- phase 2: wave = head h. fp8 fragments; lg==3 covers pad k=24..31 -> zero.
    const int h = w;
    const bool live = (lg < 3);
    const int cs = h*24 + lg*8;                // byte offset within fp8 row
    long bqA[4], aqA[4], bqB[4], aqB[4];
    #pragma unroll
    for (int i = 0; i < 4; ++i) {
        const int ro = (16*i + lr)*104 + cs;
        bqA[i] = live ? *(const long*)(q8A + ro) : 0L;
        aqA[i] = live ? *(const long*)(k8A + ro) : 0L;
        bqB[i] = live ? *(const long*)(q8B + ro) : 0L;
        aqB[i] = live ? *(const long*)(k8B + ro) : 0L;
    }
    __syncthreads();   // B2: all q8/k8 reads done -> region reusable as O staging

    f32x4 stA[4][4], stB[4][4];   // st[un][tn]: u=16un+4lg+r, t=16tn+lr (KE-scaled)
    #pragma unroll
    for (int un = 0; un < 4; ++un)
        #pragma unroll
        for (int tn = 0; tn < 4; ++tn) {
            stA[un][tn] = MFMA_FP8(aqA[un], bqA[tn], (f32x4){0.f,0.f,0.f,0.f}, 0,0,0);
            stB[un][tn] = MFMA_FP8(aqB[un], bqB[tn], (f32x4){0.f,0.f,0.f,0.f}, 0,0,0);
        }

    // no-max softmax (logits tiny), exp2 directly
    float rsA[4], rsB[4];
    #pragma unroll
    for (int tn = 0; tn < 4; ++tn) {
        float sA = 0.f, sB = 0.f;
        #pragma unroll
        for (int un = 0; un < 4; ++un)
            #pragma unroll
            for (int r = 0; r < 4; ++r) {
                const float eA = exp2f(stA[un][tn][r]);
                const float eB = exp2f(stB[un][tn][r]);
                stA[un][tn][r] = eA; sA += eA;
                stB[un][tn][r] = eB; sB += eB;
            }
        sA += __shfl_xor(sA, 16); sA += __shfl_xor(sA, 32);
        sB += __shfl_xor(sB, 16); sB += __shfl_xor(sB, 32);
        rsA[tn] = 1.f / sA;
        rsB[tn] = 1.f / sB;
    }

    // PV with permuted u (P in registers, f16). K=32 x2 per window.
    f32x4 oa0A[4], oa1A[4], oa0B[4], oa1B[4];
    #pragma unroll
    for (int tn = 0; tn < 4; ++tn) {
        oa0A[tn] = (f32x4){0.f,0.f,0.f,0.f}; oa1A[tn] = (f32x4){0.f,0.f,0.f,0.f};
        oa0B[tn] = (f32x4){0.f,0.f,0.f,0.f}; oa1B[tn] = (f32x4){0.f,0.f,0.f,0.f};
    }
    const int d1 = (16 + lr > 23) ? 23 : 16 + lr;     // clamp: garbage rows discarded
    #pragma unroll
    for (int hf = 0; hf < 2; ++hf) {
        const f16x8 av0A = *(const f16x8*)&vtA[vtidx(h*24 + lr, hf*32 + lg*8)];
        const f16x8 av1A = *(const f16x8*)&vtA[vtidx(h*24 + d1, hf*32 + lg*8)];
        const f16x8 av0B = *(const f16x8*)&vtB[vtidx(h*24 + lr, hf*32 + lg*8)];
        const f16x8 av1B = *(const f16x8*)&vtB[vtidx(h*24 + d1, hf*32 + lg*8)];
        #pragma unroll
        for (int tn = 0; tn < 4; ++tn) {
            union { f16x8 v; hf2 h2[4]; } pA, pB;
            pA.h2[0] = __builtin_amdgcn_cvt_pkrtz(stA[2*hf  ][tn][0], stA[2*hf  ][tn][1]);
            pA.h2[1] = __builtin_amdgcn_cvt_pkrtz(stA[2*hf  ][tn][2], stA[2*hf  ][tn][3]);
            pA.h2[2] = __builtin_amdgcn_cvt_pkrtz(stA[2*hf+1][tn][0], stA[2*hf+1][tn][1]);
            pA.h2[3] = __builtin_amdgcn_cvt_pkrtz(stA[2*hf+1][tn][2], stA[2*hf+1][tn][3]);
            pB.h2[0] = __builtin_amdgcn_cvt_pkrtz(stB[2*hf  ][tn][0], stB[2*hf  ][tn][1]);
            pB.h2[1] = __builtin_amdgcn_cvt_pkrtz(stB[2*hf  ][tn][2], stB[2*hf  ][tn][3]);
            pB.h2[2] = __builtin_amdgcn_cvt_pkrtz(stB[2*hf+1][tn][0], stB[2*hf+1][tn][1]);
            pB.h2[3] = __builtin_amdgcn_cvt_pkrtz(stB[2*hf+1][tn][2], stB[2*hf+1][tn][3]);
            oa0A[tn] = MFMA_K32(av0A, pA.v, oa0A[tn], 0,0,0);
            oa1A[tn] = MFMA_K32(av1A, pA.v, oa1A[tn], 0,0,0);
            oa0B[tn] = MFMA_K32(av0B, pB.v, oa0B[tn], 0,0,0);
            oa1B[tn] = MFMA_K32(av1B, pB.v, oa1B[tn], 0,0,0);
        }
    }

    // ---- preload proj fragments + bias (latency hides under epilogues + B3)
    f16x8 pf[6][3];
    #pragma unroll
    for (int n = 0; n < 6; ++n)
        #pragma unroll
        for (int kk = 0; kk < 3; ++kk)
            pf[n][kk] = *(const f16x8*)(wpL + (n*3 + kk)*512);
    float4 pb4[6];
    #pragma unroll
    for (int n = 0; n < 6; ++n)
        pb4[n] = *(const float4*)(proj_b + 16*n + 4*lg);

    // O epilogues -> Ob (f16, stride 104) overlaying q8+k8
    #pragma unroll
    for (int tn = 0; tn < 4; ++tn) {
        const int tt = 16*tn + lr;
        *(f16x4*)&ObA[tt*104 + h*24 + 4*lg] =
            pk4(oa0A[tn][0]*rsA[tn], oa0A[tn][1]*rsA[tn], oa0A[tn][2]*rsA[tn], oa0A[tn][3]*rsA[tn]);
        *(f16x4*)&ObB[tt*104 + h*24 + 4*lg] =
            pk4(oa0B[tn][0]*rsB[tn], oa0B[tn][1]*rsB[tn], oa0B[tn][2]*rsB[tn], oa0B[tn][3]*rsB[tn]);
        if (lg < 2) {                                 // d = 16..23
            *(f16x4*)&ObA[tt*104 + h*24 + 16 + 4*lg] =
                pk4(oa1A[tn][0]*rsA[tn], oa1A[tn][1]*rsA[tn], oa1A[tn][2]*rsA[tn], oa1A[tn][3]*rsA[tn]);
            *(f16x4*)&ObB[tt*104 + h*24 + 16 + 4*lg] =
                pk4(oa1B[tn][0]*rsB[tn], oa1B[tn][1]*rsB[tn], oa1B[tn][2]*rsB[tn], oa1B[tn][3]*rsB[tn]);
        }
    }
    __syncthreads();   // B3: O complete for both windows

    // ---- phase 3: proj. bo reads, barrier, then o2 (f32) overlays entire region.
    f16x8 boA[3], boB[3];
    #pragma unroll
    for (int kk = 0; kk < 3; ++kk) {
        boA[kk] = *(const f16x8*)&ObA[t*104 + kk*32 + lg*8];
        boB[kk] = *(const f16x8*)&ObB[t*104 + kk*32 + lg*8];
    }
    __syncthreads();   // B4: all O reads done -> o2 may overwrite

    #pragma unroll
    for (int n = 0; n < 6; ++n) {
        const int c0 = 16*n + 4*lg;
        f32x4 paA = {pb4[n].x, pb4[n].y, pb4[n].z, pb4[n].w};
        f32x4 paB = paA;
        #pragma unroll
        for (int kk = 0; kk < 3; ++kk) {
            paA = MFMA_K32(pf[n][kk], boA[kk], paA, 0,0,0);
            paB = MFMA_K32(pf[n][kk], boB[kk], paB, 0,0,0);
        }
        *(f32x4*)&o2A[t*100 + c0] = paA;
        *(f32x4*)&o2B[t*100 + c0] = paB;
    }
    __syncthreads();   // B5: o2 staged

    // ---- coalesced fp32 stores (384 B contiguous per token)
    #pragma unroll
    for (int it = 0; it < 6; ++it) {
        const int i = it*256 + tid;
        const int tt = i / 24, c4 = (i - tt*24) * 4;
        const size_t po = win_baseA + (size_t)(((tt>>3)<<8) + (tt&7))*96 + c4;
        *(float4*)(out + po)       = *(const float4*)&o2A[tt*100 + c4];
        *(float4*)(out + po + 768) = *(const float4*)&o2B[tt*100 + c4];
    }
}

extern "C" void kernel_launch(void* const* d_in, const int* in_sizes, int n_in,
                              void* d_out, int out_size, void* d_ws, size_t ws_size,
                              hipStream_t stream) {
    const float* x      = (const float*)d_in[0];
    const float* qkv_w  = (const float*)d_in[1];
    const float* qkv_b  = (const float*)d_in[2];
    const float* proj_w = (const float*)d_in[3];
    const float* proj_b = (const float*)d_in[4];
    float* out = (float*)d_out;
    f16* ws = (f16*)d_ws;   // 3456 qw frags | 1152 pw frags | scaled q-bias (96 f32)

    prep_weights<<<dim3(19), dim3(256), 0, stream>>>(qkv_w, proj_w, qkv_b, ws);
    winattn<<<dim3(4096), dim3(256), 0, stream>>>(x, ws, qkv_b, ws + 27648, proj_b, out);
}

// Round 13
// 150.434 us; speedup vs baseline: 1.1679x; 1.1679x over previous
//
#include <hip/hip_runtime.h>
#include <stdint.h>

// WindowAttention B=8 H=W=256 C=96 ws=8 heads=4 hd=24 — MFMA, mixed fp8/f16.
// R13 = R12 (fp8 q/k staging, 51200 B LDS -> 3 blocks/CU) with spill fixes:
//   - P packed to f16 fragments BEFORE PV (st[] dies early, -64 VGPR at peak)
//   - biases added in epilogue (short float4 liveness), not MFMA C-init

typedef _Float16 f16;
typedef f16 f16x8 __attribute__((ext_vector_type(8)));
typedef f16 f16x4 __attribute__((ext_vector_type(4)));
typedef __fp16 hf2 __attribute__((ext_vector_type(2)));
typedef float f32x4 __attribute__((ext_vector_type(4)));

#define MFMA_K32  __builtin_amdgcn_mfma_f32_16x16x32_f16       // A/B f16x8
#define MFMA_FP8  __builtin_amdgcn_mfma_f32_16x16x32_fp8_fp8   // A/B long (8 fp8)

#define KE 0.29448890f  // 24^-0.5 * log2(e), folded into Q weights+bias

__device__ __forceinline__ int vtidx(int row, int col) { return row*64 + (col ^ ((row & 7) << 3)); }

__device__ __forceinline__ f16x4 pk4(float a, float b, float c, float d) {
    union { f16x4 v; hf2 h[2]; } u;
    u.h[0] = __builtin_amdgcn_cvt_pkrtz(a, b);
    u.h[1] = __builtin_amdgcn_cvt_pkrtz(c, d);
    return u.v;
}

__device__ __forceinline__ int pk_fp8x4(float a, float b, float c, float d) {
    int v = __builtin_amdgcn_cvt_pk_fp8_f32(a, b, 0, false);   // low 16 bits
    v = __builtin_amdgcn_cvt_pk_fp8_f32(c, d, v, true);        // high 16 bits
    return v;
}

// Prepack weights into per-wave MFMA fragment order (q-rows pre-scaled by KE);
// scaled q-bias (float[96]) at f16 offset 36864.
__global__ void prep_weights(const float* __restrict__ qkv_w,
                             const float* __restrict__ proj_w,
                             const float* __restrict__ qkv_b,
                             f16* __restrict__ ws) {
    const int u = blockIdx.x * 256 + threadIdx.x;
    if (u < 3456) {
        const int lane = u & 63, unit = u >> 6;
        const int n = unit / 3, kk = unit - 3*n;
        const int lr = lane & 15, lg = lane >> 4;
        const float sc = (n < 6) ? KE : 1.0f;
        const float* s = qkv_w + (16*n + lr)*96 + kk*32 + lg*8;
        f16x8 v;
        #pragma unroll
        for (int e = 0; e < 8; ++e) v[e] = (f16)(s[e] * sc);
        *(f16x8*)(ws + (size_t)u*8) = v;
    } else if (u < 4608) {
        const int uu = u - 3456;
        const int lane = uu & 63, unit = uu >> 6;
        const int n = unit / 3, kk = unit - 3*n;
        const int lr = lane & 15, lg = lane >> 4;
        const float* s = proj_w + (16*n + lr)*96 + kk*32 + lg*8;
        f16x8 v;
        #pragma unroll
        for (int e = 0; e < 8; ++e) v[e] = (f16)s[e];
        *(f16x8*)(ws + 27648 + (size_t)uu*8) = v;
    } else if (u < 4704) {
        const int j = u - 4608;
        ((float*)(ws + 36864))[j] = qkv_b[j] * KE;
    }
}

__global__ __launch_bounds__(256, 3) void winattn(
    const float* __restrict__ x,
    const f16*   __restrict__ wsq,     // prepacked qkv_w fragments (+ scaled q-bias)
    const float* __restrict__ qkv_b,   // [288] (k/v bias raw)
    const f16*   __restrict__ wsp,     // prepacked proj_w fragments
    const float* __restrict__ proj_b,  // [96]
    float* __restrict__ out)
{
    // Per-window region (25600 B): q8[64x104B] | k8[64x104B] | vt f16[96x64]
    //   After B2: O f16 [64][104] overlays q8+k8. After B4: o2 f32 [64][100] overlays all.
    __shared__ __align__(16) char smem[51200];
    uint8_t* q8A = (uint8_t*)smem;
    uint8_t* k8A = q8A + 6656;
    f16* vtA = (f16*)(smem + 13312);
    f16* ObA = (f16*)smem;
    float* o2A = (float*)smem;
    uint8_t* q8B = (uint8_t*)(smem + 25600);
    uint8_t* k8B = q8B + 6656;
    f16* vtB = (f16*)(smem + 25600 + 13312);
    f16* ObB = (f16*)(smem + 25600);
    float* o2B = (float*)(smem + 25600);

    const int tid = threadIdx.x;
    const int wid = blockIdx.x * 2;            // window A; B = wid+1 (same row)
    const int bb = wid >> 10, wh = (wid >> 5) & 31, ww = wid & 31;
    const size_t win_baseA = ((size_t)(bb*256 + wh*8)*256 + (size_t)(ww*8)) * 96;

    const int lane = tid & 63, w = tid >> 6;
    const int lr = lane & 15, lg = lane >> 4;
    const int t = 16*w + lr;                   // this lane's token (phases 1,3)
    const size_t tok_offA = win_baseA + (size_t)(((t>>3)<<8) + (t&7))*96;
    const size_t tok_offB = tok_offA + 768;    // +8 pixels * 96 ch

    const f16* wqL = wsq + lane*8;             // per-lane fragment base (qkv)
    const f16* wpL = wsp + lane*8;             // per-lane fragment base (proj)
    const float* qbs = (const float*)(wsq + 36864);  // scaled q-bias

    // ---- phase 1: x fragments for both windows (12 dwordx4 loads in flight)
    f16x8 axA[3], axB[3];
    #pragma unroll
    for (int kk = 0; kk < 3; ++kk) {
        const float* xpA = x + tok_offA + kk*32 + lg*8;
        const float* xpB = x + tok_offB + kk*32 + lg*8;
        const float4 a0 = *(const float4*)xpA;
        const float4 a1 = *(const float4*)(xpA + 4);
        const float4 b0 = *(const float4*)xpB;
        const float4 b1 = *(const float4*)(xpB + 4);
        union { f16x8 v; f16x4 q[2]; } ua, ub;
        ua.q[0] = pk4(a0.x, a0.y, a0.z, a0.w);
        ua.q[1] = pk4(a1.x, a1.y, a1.z, a1.w);
        ub.q[0] = pk4(b0.x, b0.y, b0.z, b0.w);
        ub.q[1] = pk4(b1.x, b1.y, b1.z, b1.w);
        axA[kk] = ua.v;
        axB[kk] = ub.v;
    }
    // permuted v^T column for this lane's token t (u_k with perm(u_k) = t)
    const int vcol = (w>>1)*32 + (lr>>2)*8 + (w&1)*4 + (lr&3);

    // ======== Q group (n=0..5): weights loaded ONCE; bias added in epilogue; fp8 pack
    {
        f16x8 wf[6][3];
        #pragma unroll
        for (int nn = 0; nn < 6; ++nn)
            #pragma unroll
            for (int kk = 0; kk < 3; ++kk)
                wf[nn][kk] = *(const f16x8*)(wqL + (nn*3 + kk)*512);
        #pragma unroll
        for (int nn = 0; nn < 6; ++nn) {
            f32x4 accA = {0.f,0.f,0.f,0.f}, accB = {0.f,0.f,0.f,0.f};
            #pragma unroll
            for (int kk = 0; kk < 3; ++kk) {
                accA = MFMA_K32(wf[nn][kk], axA[kk], accA, 0,0,0);
                accB = MFMA_K32(wf[nn][kk], axB[kk], accB, 0,0,0);
            }
            const int j0 = 16*nn + 4*lg;
            const float4 b4 = *(const float4*)(qbs + j0);      // scaled q-bias
            *(int*)(q8A + t*104 + j0) = pk_fp8x4(accA[0]+b4.x, accA[1]+b4.y, accA[2]+b4.z, accA[3]+b4.w);
            *(int*)(q8B + t*104 + j0) = pk_fp8x4(accB[0]+b4.x, accB[1]+b4.y, accB[2]+b4.z, accB[3]+b4.w);
        }
    }
    // ======== K group (n=6..11)
    {
        f16x8 wf[6][3];
        #pragma unroll
        for (int nn = 0; nn < 6; ++nn)
            #pragma unroll
            for (int kk = 0; kk < 3; ++kk)
                wf[nn][kk] = *(const f16x8*)(wqL + ((nn+6)*3 + kk)*512);
        #pragma unroll
        for (int nn = 0; nn < 6; ++nn) {
            f32x4 accA = {0.f,0.f,0.f,0.f}, accB = {0.f,0.f,0.f,0.f};
            #pragma unroll
            for (int kk = 0; kk < 3; ++kk) {
                accA = MFMA_K32(wf[nn][kk], axA[kk], accA, 0,0,0);
                accB = MFMA_K32(wf[nn][kk], axB[kk], accB, 0,0,0);
            }
            const int j0 = 16*nn + 4*lg;
            const float4 b4 = *(const float4*)(qkv_b + 96 + j0);
            *(int*)(k8A + t*104 + j0) = pk_fp8x4(accA[0]+b4.x, accA[1]+b4.y, accA[2]+b4.z, accA[3]+b4.w);
            *(int*)(k8B + t*104 + j0) = pk_fp8x4(accB[0]+b4.x, accB[1]+b4.y, accB[2]+b4.z, accB[3]+b4.w);
        }
    }
    // ======== V group (n=12..17) -> vt (f16) permuted columns
    {
        f16x8 wf[6][3];
        #pragma unroll
        for (int nn = 0; nn < 6; ++nn)
            #pragma unroll
            for (int kk = 0; kk < 3; ++kk)
                wf[nn][kk] = *(const f16x8*)(wqL + ((nn+12)*3 + kk)*512);
        #pragma unroll
        for (int nn = 0; nn < 6; ++nn) {
            f32x4 accA = {0.f,0.f,0.f,0.f}, accB = {0.f,0.f,0.f,0.f};
            #pragma unroll
            for (int kk = 0; kk < 3; ++kk) {
                accA = MFMA_K32(wf[nn][kk], axA[kk], accA, 0,0,0);
                accB = MFMA_K32(wf[nn][kk], axB[kk], accB, 0,0,0);
            }
            const int j0 = 16*nn + 4*lg;
            const float4 b4 = *(const float4*)(qkv_b + 192 + j0);
            const int hv = (unsigned)j0 / 24u, d0 = j0 - 24*hv;
            vtA[vtidx(hv*24 + d0+0, vcol)] = (f16)(accA[0]+b4.x);
            vtA[vtidx(hv*24 + d0+1, vcol)] = (f16)(accA[1]+b4.y);
            vtA[vtidx(hv*24 + d0+2, vcol)] = (f16)(accA[2]+b4.z);
            vtA[vtidx(hv*24 + d0+3, vcol)] = (f16)(accA[3]+b4.w);
            vtB[vtidx(hv*24 + d0+0, vcol)] = (f16)(accB[0]+b4.x);
            vtB[vtidx(hv*24 + d0+1, vcol)] = (f16)(accB[1]+b4.y);
            vtB[vtidx(hv*24 + d0+2, vcol)] = (f16)(accB[2]+b4.z);
            vtB[vtidx(hv*24 + d0+3, vcol)] = (f16)(accB[3]+b4.w);
        }
    }
    __syncthreads();   // B1: q8/k8/vt staged for both windows

    // ---- phase 2: wave = head h. fp8 fragments; lg==3 covers pad k=24..31 -> zero.
    const int h = w;
    const bool live = (lg < 3);
    const int cs = h*24 + lg*8;                // byte offset within fp8 row
    long bqA[4], aqA[4], bqB[4], aqB[4];
    #pragma unroll
    for (int i = 0; i < 4; ++i) {
        const int ro = (16*i + lr)*104 + cs;
        bqA[i] = live ? *(const long*)(q8A + ro) : 0L;
        aqA[i] = live ? *(const long*)(k8A + ro) : 0L;
        bqB[i] = live ? *(const long*)(q8B + ro) : 0L;
        aqB[i] = live ? *(const long*)(k8B + ro) : 0L;
    }
    __syncthreads();   // B2: all q8/k8 reads done -> region reusable as O staging

    f32x4 stA[4][4], stB[4][4];   // st[un][tn]: u=16un+4lg+r, t=16tn+lr (KE-scaled)
    #pragma unroll
    for (int un = 0; un < 4; ++un)
        #pragma unroll
        for (int tn = 0; tn < 4; ++tn) {
            stA[un][tn] = MFMA_FP8(aqA[un], bqA[tn], (f32x4){0.f,0.f,0.f,0.f}, 0,0,0);
            stB[un][tn] = MFMA_FP8(aqB[un], bqB[tn], (f32x4){0.f,0.f,0.f,0.f}, 0,0,0);
        }

    // no-max softmax (logits tiny), exp2 directly
    float rsA[4], rsB[4];
    #pragma unroll
    for (int tn = 0; tn < 4; ++tn) {
        float sA = 0.f, sB = 0.f;
        #pragma unroll
        for (int un = 0; un < 4; ++un)
            #pragma unroll
            for (int r = 0; r < 4; ++r) {
                const float eA = exp2f(stA[un][tn][r]);
                const float eB = exp2f(stB[un][tn][r]);
                stA[un][tn][r] = eA; sA += eA;
                stB[un][tn][r] = eB; sB += eB;
            }
        sA += __shfl_xor(sA, 16); sA += __shfl_xor(sA, 32);
        sB += __shfl_xor(sB, 16); sB += __shfl_xor(sB, 32);
        rsA[tn] = 1.f / sA;
        rsB[tn] = 1.f / sB;
    }

    // pack P -> f16 fragments NOW (st dies here; -64 VGPR during PV)
    f16x8 pbA[2][4], pbB[2][4];
    #pragma unroll
    for (int hf = 0; hf < 2; ++hf)
        #pragma unroll
        for (int tn = 0; tn < 4; ++tn) {
            union { f16x8 v; hf2 h2[4]; } uA, uB;
            uA.h2[0] = __builtin_amdgcn_cvt_pkrtz(stA[2*hf  ][tn][0], stA[2*hf  ][tn][1]);
            uA.h2[1] = __builtin_amdgcn_cvt_pkrtz(stA[2*hf  ][tn][2], stA[2*hf  ][tn][3]);
            uA.h2[2] = __builtin_amdgcn_cvt_pkrtz(stA[2*hf+1][tn][0], stA[2*hf+1][tn][1]);
            uA.h2[3] = __builtin_amdgcn_cvt_pkrtz(stA[2*hf+1][tn][2], stA[2*hf+1][tn][3]);
            uB.h2[0] = __builtin_amdgcn_cvt_pkrtz(stB[2*hf  ][tn][0], stB[2*hf  ][tn][1]);
            uB.h2[1] = __builtin_amdgcn_cvt_pkrtz(stB[2*hf  ][tn][2], stB[2*hf  ][tn][3]);
            uB.h2[2] = __builtin_amdgcn_cvt_pkrtz(stB[2*hf+1][tn][0], stB[2*hf+1][tn][1]);
            uB.h2[3] = __builtin_amdgcn_cvt_pkrtz(stB[2*hf+1][tn][2], stB[2*hf+1][tn][3]);
            pbA[hf][tn] = uA.v;
            pbB[hf][tn] = uB.v;
        }

    // PV with permuted u (P in registers, f16). K=32 x2 per window.
    f32x4 oa0A[4], oa1A[4], oa0B[4], oa1B[4];
    #pragma unroll
    for (int tn = 0; tn < 4; ++tn) {
        oa0A[tn] = (f32x4){0.f,0.f,0.f,0.f}; oa1A[tn] = (f32x4){0.f,0.f,0.f,0.f};
        oa0B[tn] = (f32x4){0.f,0.f,0.f,0.f}; oa1B[tn] = (f32x4){0.f,0.f,0.f,0.f};
    }
    const int d1 = (16 + lr > 23) ? 23 : 16 + lr;     // clamp: garbage rows discarded
    #pragma unroll
    for (int hf = 0; hf < 2; ++hf) {
        const f16x8 av0A = *(const f16x8*)&vtA[vtidx(h*24 + lr, hf*32 + lg*8)];
        const f16x8 av1A = *(const f16x8*)&vtA[vtidx(h*24 + d1, hf*32 + lg*8)];
        const f16x8 av0B = *(const f16x8*)&vtB[vtidx(h*24 + lr, hf*32 + lg*8)];
        const f16x8 av1B = *(const f16x8*)&vtB[vtidx(h*24 + d1, hf*32 + lg*8)];
        #pragma unroll
        for (int tn = 0; tn < 4; ++tn) {
            oa0A[tn] = MFMA_K32(av0A, pbA[hf][tn], oa0A[tn], 0,0,0);
            oa1A[tn] = MFMA_K32(av1A, pbA[hf][tn], oa1A[tn], 0,0,0);
            oa0B[tn] = MFMA_K32(av0B, pbB[hf][tn], oa0B[tn], 0,0,0);
            oa1B[tn] = MFMA_K32(av1B, pbB[hf][tn], oa1B[tn], 0,0,0);
        }
    }

    // ---- preload proj fragments + bias (latency hides under epilogues + B3)
    f16x8 pf[6][3];
    #pragma unroll
    for (int n = 0; n < 6; ++n)
        #pragma unroll
        for (int kk = 0; kk < 3; ++kk)
            pf[n][kk] = *(const f16x8*)(wpL + (n*3 + kk)*512);
    float4 pb4[6];
    #pragma unroll
    for (int n = 0; n < 6; ++n)
        pb4[n] = *(const float4*)(proj_b + 16*n + 4*lg);

    // O epilogues -> Ob (f16, stride 104) overlaying q8+k8
    #pragma unroll
    for (int tn = 0; tn < 4; ++tn) {
        const int tt = 16*tn + lr;
        *(f16x4*)&ObA[tt*104 + h*24 + 4*lg] =
            pk4(oa0A[tn][0]*rsA[tn], oa0A[tn][1]*rsA[tn], oa0A[tn][2]*rsA[tn], oa0A[tn][3]*rsA[tn]);
        *(f16x4*)&ObB[tt*104 + h*24 + 4*lg] =
            pk4(oa0B[tn][0]*rsB[tn], oa0B[tn][1]*rsB[tn], oa0B[tn][2]*rsB[tn], oa0B[tn][3]*rsB[tn]);
        if (lg < 2) {                                 // d = 16..23
            *(f16x4*)&ObA[tt*104 + h*24 + 16 + 4*lg] =
                pk4(oa1A[tn][0]*rsA[tn], oa1A[tn][1]*rsA[tn], oa1A[tn][2]*rsA[tn], oa1A[tn][3]*rsA[tn]);
            *(f16x4*)&ObB[tt*104 + h*24 + 16 + 4*lg] =
                pk4(oa1B[tn][0]*rsB[tn], oa1B[tn][1]*rsB[tn], oa1B[tn][2]*rsB[tn], oa1B[tn][3]*rsB[tn]);
        }
    }
    __syncthreads();   // B3: O complete for both windows

    // ---- phase 3: proj. bo reads, barrier, then o2 (f32) overlays entire region.
    f16x8 boA[3], boB[3];
    #pragma unroll
    for (int kk = 0; kk < 3; ++kk) {
        boA[kk] = *(const f16x8*)&ObA[t*104 + kk*32 + lg*8];
        boB[kk] = *(const f16x8*)&ObB[t*104 + kk*32 + lg*8];
    }
    __syncthreads();   // B4: all O reads done -> o2 may overwrite

    #pragma unroll
    for (int n = 0; n < 6; ++n) {
        const int c0 = 16*n + 4*lg;
        f32x4 paA = {pb4[n].x, pb4[n].y, pb4[n].z, pb4[n].w};
        f32x4 paB = paA;
        #pragma unroll
        for (int kk = 0; kk < 3; ++kk) {
            paA = MFMA_K32(pf[n][kk], boA[kk], paA, 0,0,0);
            paB = MFMA_K32(pf[n][kk], boB[kk], paB, 0,0,0);
        }
        *(f32x4*)&o2A[t*100 + c0] = paA;
        *(f32x4*)&o2B[t*100 + c0] = paB;
    }
    __syncthreads();   // B5: o2 staged

    // ---- coalesced fp32 stores (384 B contiguous per token)
    #pragma unroll
    for (int it = 0; it < 6; ++it) {
        const int i = it*256 + tid;
        const int tt = i / 24, c4 = (i - tt*24) * 4;
        const size_t po = win_baseA + (size_t)(((tt>>3)<<8) + (tt&7))*96 + c4;
        *(float4*)(out + po)       = *(const float4*)&o2A[tt*100 + c4];
        *(float4*)(out + po + 768) = *(const float4*)&o2B[tt*100 + c4];
    }
}

extern "C" void kernel_launch(void* const* d_in, const int* in_sizes, int n_in,
                              void* d_out, int out_size, void* d_ws, size_t ws_size,
                              hipStream_t stream) {
    const float* x      = (const float*)d_in[0];
    const float* qkv_w  = (const float*)d_in[1];
    const float* qkv_b  = (const float*)d_in[2];
    const float* proj_w = (const float*)d_in[3];
    const float* proj_b = (const float*)d_in[4];
    float* out = (float*)d_out;
    f16* ws = (f16*)d_ws;   // 3456 qw frags | 1152 pw frags | scaled q-bias (96 f32)

    prep_weights<<<dim3(19), dim3(256), 0, stream>>>(qkv_w, proj_w, qkv_b, ws);
    winattn<<<dim3(4096), dim3(256), 0, stream>>>(x, ws, qkv_b, ws + 27648, proj_b, out);
}

// Round 14
// 139.002 us; speedup vs baseline: 1.2640x; 1.0822x over previous
//
#include <hip/hip_runtime.h>

// WindowAttention B=8 H=W=256 C=96 ws=8 heads=4 hd=24 — fp16 MFMA.
// R14 = R11 (2 windows/block, prepacked weights, no-max softmax, o2-staged stores) +
//   - P packed to f16 fragments EARLY (st dies before PV, -64 VGPR at peak)
//   - softmax denominators via MFMA row-sum with all-ones A-fragment:
//     16 MFMAs on the idle matrix pipe replace 32 shfl_xor + 256 VALU adds,
//     zero cross-lane traffic (sum is u-permutation invariant).

typedef _Float16 f16;
typedef f16 f16x8 __attribute__((ext_vector_type(8)));
typedef f16 f16x4 __attribute__((ext_vector_type(4)));
typedef __fp16 hf2 __attribute__((ext_vector_type(2)));   // cvt_pkrtz result type
typedef float f32x4 __attribute__((ext_vector_type(4)));

#define MFMA_K32 __builtin_amdgcn_mfma_f32_16x16x32_f16   // A/B f16x8

#define QS 104        // q/k/O row stride in f16 (208 B -> 2-way bank alias, free)
#define KE 0.29448890f // 24^-0.5 * log2(e), folded into Q weights+bias

// vt rows 64 f16 wide, XOR-swizzled 16-B octets: conflict-free b128 reads
__device__ __forceinline__ int vtidx(int row, int col) { return row*64 + (col ^ ((row & 7) << 3)); }
// o2 f32 rows stride 104, XOR-swizzled 16-B quads
__device__ __forceinline__ int o2idx(int t, int c)     { return t*104 + (c ^ ((t & 7) << 2)); }

__device__ __forceinline__ f16x4 pk4(float a, float b, float c, float d) {
    union { f16x4 v; hf2 h[2]; } u;
    u.h[0] = __builtin_amdgcn_cvt_pkrtz(a, b);
    u.h[1] = __builtin_amdgcn_cvt_pkrtz(c, d);
    return u.v;
}

// Prepack weights into per-wave MFMA fragment order (q-rows pre-scaled by KE);
// scaled q-bias (float[96]) at f16 offset 36864.
__global__ void prep_weights(const float* __restrict__ qkv_w,
                             const float* __restrict__ proj_w,
                             const float* __restrict__ qkv_b,
                             f16* __restrict__ ws) {
    const int u = blockIdx.x * 256 + threadIdx.x;
    if (u < 3456) {
        const int lane = u & 63, unit = u >> 6;
        const int n = unit / 3, kk = unit - 3*n;
        const int lr = lane & 15, lg = lane >> 4;
        const float sc = (n < 6) ? KE : 1.0f;
        const float* s = qkv_w + (16*n + lr)*96 + kk*32 + lg*8;
        f16x8 v;
        #pragma unroll
        for (int e = 0; e < 8; ++e) v[e] = (f16)(s[e] * sc);
        *(f16x8*)(ws + (size_t)u*8) = v;
    } else if (u < 4608) {
        const int uu = u - 3456;
        const int lane = uu & 63, unit = uu >> 6;
        const int n = unit / 3, kk = unit - 3*n;
        const int lr = lane & 15, lg = lane >> 4;
        const float* s = proj_w + (16*n + lr)*96 + kk*32 + lg*8;
        f16x8 v;
        #pragma unroll
        for (int e = 0; e < 8; ++e) v[e] = (f16)s[e];
        *(f16x8*)(ws + 27648 + (size_t)uu*8) = v;
    } else if (u < 4704) {
        const int j = u - 4608;                       // 0..95: scaled q-bias
        ((float*)(ws + 36864))[j] = qkv_b[j] * KE;
    }
}

__global__ __launch_bounds__(256, 2) void winattn(
    const float* __restrict__ x,
    const f16*   __restrict__ wsq,     // prepacked qkv_w fragments (+ scaled q-bias)
    const float* __restrict__ qkv_b,   // [288] (k/v bias raw)
    const f16*   __restrict__ wsp,     // prepacked proj_w fragments
    const float* __restrict__ proj_b,  // [96]
    float* __restrict__ out)
{
    // manual layout so o2 (f32) can overlay dead q/k regions after proj reads
    __shared__ __align__(16) char smem[77824];
    f16* qqA = (f16*)(smem);            // 13312 B  q win A; O_A after B2
    f16* qkA = (f16*)(smem + 13312);    // 13312 B
    f16* qqB = (f16*)(smem + 26624);    // 13312 B
    f16* qkB = (f16*)(smem + 39936);    // 13312 B
    f16* vtA = (f16*)(smem + 53248);    // 12288 B  v^T win A, swizzled
    f16* vtB = (f16*)(smem + 65536);    // 12288 B
    float* o2A = (float*)(smem);        // 26624 B  overlays qqA+qkA after B4
    float* o2B = (float*)(smem + 26624);// 26624 B  overlays qqB+qkB after B4

    const int tid = threadIdx.x;
    const int wid = blockIdx.x * 2;            // window A; B = wid+1 (same row)
    const int bb = wid >> 10, wh = (wid >> 5) & 31, ww = wid & 31;
    const size_t win_baseA = ((size_t)(bb*256 + wh*8)*256 + (size_t)(ww*8)) * 96;

    const int lane = tid & 63, w = tid >> 6;
    const int lr = lane & 15, lg = lane >> 4;
    const int t = 16*w + lr;                   // this lane's token (phases 1,3)
    const size_t tok_offA = win_baseA + (size_t)(((t>>3)<<8) + (t&7))*96;
    const size_t tok_offB = tok_offA + 768;    // +8 pixels * 96 ch

    const f16* wqL = wsq + lane*8;             // per-lane fragment base (qkv)
    const f16* wpL = wsp + lane*8;             // per-lane fragment base (proj)
    const float* qbs = (const float*)(wsq + 36864);  // scaled q-bias

    // ---- phase 1: x fragments for both windows (12 dwordx4 loads in flight)
    f16x8 axA[3], axB[3];
    #pragma unroll
    for (int kk = 0; kk < 3; ++kk) {
        const float* xpA = x + tok_offA + kk*32 + lg*8;
        const float* xpB = x + tok_offB + kk*32 + lg*8;
        const float4 a0 = *(const float4*)xpA;
        const float4 a1 = *(const float4*)(xpA + 4);
        const float4 b0 = *(const float4*)xpB;
        const float4 b1 = *(const float4*)(xpB + 4);
        union { f16x8 v; f16x4 q[2]; } ua, ub;
        ua.q[0] = pk4(a0.x, a0.y, a0.z, a0.w);
        ua.q[1] = pk4(a1.x, a1.y, a1.z, a1.w);
        ub.q[0] = pk4(b0.x, b0.y, b0.z, b0.w);
        ub.q[1] = pk4(b1.x, b1.y, b1.z, b1.w);
        axA[kk] = ua.v;
        axB[kk] = ub.v;
    }
    // permuted v^T column for this lane's token t (u_k with perm(u_k) = t)
    const int vcol = (w>>1)*32 + (lr>>2)*8 + (w&1)*4 + (lr&3);

    // ======== Q group (n=0..5): weights loaded ONCE, used for A and B (pre-scaled by KE)
    {
        f16x8 wf[6][3];
        #pragma unroll
        for (int nn = 0; nn < 6; ++nn)
            #pragma unroll
            for (int kk = 0; kk < 3; ++kk)
                wf[nn][kk] = *(const f16x8*)(wqL + (nn*3 + kk)*512);
        #pragma unroll
        for (int nn = 0; nn < 6; ++nn) {
            f32x4 accA = {0.f,0.f,0.f,0.f}, accB = {0.f,0.f,0.f,0.f};
            #pragma unroll
            for (int kk = 0; kk < 3; ++kk) {
                accA = MFMA_K32(wf[nn][kk], axA[kk], accA, 0,0,0);
                accB = MFMA_K32(wf[nn][kk], axB[kk], accB, 0,0,0);
            }
            const int j0 = 16*nn + 4*lg;
            const float4 b4 = *(const float4*)(qbs + j0);      // scaled q-bias
            *(f16x4*)&qqA[t*QS + j0] = pk4(accA[0]+b4.x, accA[1]+b4.y, accA[2]+b4.z, accA[3]+b4.w);
            *(f16x4*)&qqB[t*QS + j0] = pk4(accB[0]+b4.x, accB[1]+b4.y, accB[2]+b4.z, accB[3]+b4.w);
        }
    }
    // ======== K group (n=6..11)
    {
        f16x8 wf[6][3];
        #pragma unroll
        for (int nn = 0; nn < 6; ++nn)
            #pragma unroll
            for (int kk = 0; kk < 3; ++kk)
                wf[nn][kk] = *(const f16x8*)(wqL + ((nn+6)*3 + kk)*512);
        #pragma unroll
        for (int nn = 0; nn < 6; ++nn) {
            f32x4 accA = {0.f,0.f,0.f,0.f}, accB = {0.f,0.f,0.f,0.f};
            #pragma unroll
            for (int kk = 0; kk < 3; ++kk) {
                accA = MFMA_K32(wf[nn][kk], axA[kk], accA, 0,0,0);
                accB = MFMA_K32(wf[nn][kk], axB[kk], accB, 0,0,0);
            }
            const int j0 = 16*nn + 4*lg;
            const float4 b4 = *(const float4*)(qkv_b + 96 + j0);
            *(f16x4*)&qkA[t*QS + j0] = pk4(accA[0]+b4.x, accA[1]+b4.y, accA[2]+b4.z, accA[3]+b4.w);
            *(f16x4*)&qkB[t*QS + j0] = pk4(accB[0]+b4.x, accB[1]+b4.y, accB[2]+b4.z, accB[3]+b4.w);
        }
    }
    // ======== V group (n=12..17) -> vt permuted columns
    {
        f16x8 wf[6][3];
        #pragma unroll
        for (int nn = 0; nn < 6; ++nn)
            #pragma unroll
            for (int kk = 0; kk < 3; ++kk)
                wf[nn][kk] = *(const f16x8*)(wqL + ((nn+12)*3 + kk)*512);
        #pragma unroll
        for (int nn = 0; nn < 6; ++nn) {
            f32x4 accA = {0.f,0.f,0.f,0.f}, accB = {0.f,0.f,0.f,0.f};
            #pragma unroll
            for (int kk = 0; kk < 3; ++kk) {
                accA = MFMA_K32(wf[nn][kk], axA[kk], accA, 0,0,0);
                accB = MFMA_K32(wf[nn][kk], axB[kk], accB, 0,0,0);
            }
            const int j0 = 16*nn + 4*lg;
            const float4 b4 = *(const float4*)(qkv_b + 192 + j0);
            const int hv = (unsigned)j0 / 24u, d0 = j0 - 24*hv;
            vtA[vtidx(hv*24 + d0+0, vcol)] = (f16)(accA[0]+b4.x);
            vtA[vtidx(hv*24 + d0+1, vcol)] = (f16)(accA[1]+b4.y);
            vtA[vtidx(hv*24 + d0+2, vcol)] = (f16)(accA[2]+b4.z);
            vtA[vtidx(hv*24 + d0+3, vcol)] = (f16)(accA[3]+b4.w);
            vtB[vtidx(hv*24 + d0+0, vcol)] = (f16)(accB[0]+b4.x);
            vtB[vtidx(hv*24 + d0+1, vcol)] = (f16)(accB[1]+b4.y);
            vtB[vtidx(hv*24 + d0+2, vcol)] = (f16)(accB[2]+b4.z);
            vtB[vtidx(hv*24 + d0+3, vcol)] = (f16)(accB[3]+b4.w);
        }
    }
    __syncthreads();   // B1: q/k/v staged for both windows

    // ---- phase 2: wave = head h, both windows. lg==3 fragments are pure pad -> zero reg.
    const int h = w;
    const bool live = (lg < 3);
    const int cs = h*24 + lg*8;
    const f16x8 z8 = {0,0,0,0,0,0,0,0};

    f16x8 bfA[4], afA[4], bfB[4], afB[4];
    #pragma unroll
    for (int i = 0; i < 4; ++i) {
        bfA[i] = z8; afA[i] = z8; bfB[i] = z8; afB[i] = z8;
        if (live) {
            bfA[i] = *(const f16x8*)&qqA[(16*i + lr)*QS + cs];
            afA[i] = *(const f16x8*)&qkA[(16*i + lr)*QS + cs];
            bfB[i] = *(const f16x8*)&qqB[(16*i + lr)*QS + cs];
            afB[i] = *(const f16x8*)&qkB[(16*i + lr)*QS + cs];
        }
    }
    __syncthreads();   // B2: qq reads done -> qqA/qqB reusable as O staging

    f32x4 stA[4][4], stB[4][4];   // st[un][tn]: u=16un+4lg+r, t=16tn+lr (KE-scaled)
    #pragma unroll
    for (int un = 0; un < 4; ++un)
        #pragma unroll
        for (int tn = 0; tn < 4; ++tn) {
            stA[un][tn] = MFMA_K32(afA[un], bfA[tn], (f32x4){0.f,0.f,0.f,0.f}, 0,0,0);
            stB[un][tn] = MFMA_K32(afB[un], bfB[tn], (f32x4){0.f,0.f,0.f,0.f}, 0,0,0);
        }

    // no-max softmax: exp2 in place (logits tiny)
    #pragma unroll
    for (int un = 0; un < 4; ++un)
        #pragma unroll
        for (int tn = 0; tn < 4; ++tn)
            #pragma unroll
            for (int r = 0; r < 4; ++r) {
                stA[un][tn][r] = exp2f(stA[un][tn][r]);
                stB[un][tn][r] = exp2f(stB[un][tn][r]);
            }

    // pack P -> f16 fragments EARLY (st dies here)
    f16x8 pbA[2][4], pbB[2][4];
    #pragma unroll
    for (int hf = 0; hf < 2; ++hf)
        #pragma unroll
        for (int tn = 0; tn < 4; ++tn) {
            union { f16x8 v; hf2 h2[4]; } uA, uB;
            uA.h2[0] = __builtin_amdgcn_cvt_pkrtz(stA[2*hf  ][tn][0], stA[2*hf  ][tn][1]);
            uA.h2[1] = __builtin_amdgcn_cvt_pkrtz(stA[2*hf  ][tn][2], stA[2*hf  ][tn][3]);
            uA.h2[2] = __builtin_amdgcn_cvt_pkrtz(stA[2*hf+1][tn][0], stA[2*hf+1][tn][1]);
            uA.h2[3] = __builtin_amdgcn_cvt_pkrtz(stA[2*hf+1][tn][2], stA[2*hf+1][tn][3]);
            uB.h2[0] = __builtin_amdgcn_cvt_pkrtz(stB[2*hf  ][tn][0], stB[2*hf  ][tn][1]);
            uB.h2[1] = __builtin_amdgcn_cvt_pkrtz(stB[2*hf  ][tn][2], stB[2*hf  ][tn][3]);
            uB.h2[2] = __builtin_amdgcn_cvt_pkrtz(stB[2*hf+1][tn][0], stB[2*hf+1][tn][1]);
            uB.h2[3] = __builtin_amdgcn_cvt_pkrtz(stB[2*hf+1][tn][2], stB[2*hf+1][tn][3]);
            pbA[hf][tn] = uA.v;
            pbB[hf][tn] = uB.v;
        }

    // denominators via MFMA row-sum: D = ones * P^T -> every lane holds sum[t=16tn+lr]
    const f16x8 ones8 = {1,1,1,1,1,1,1,1};
    float rsA[4], rsB[4];
    #pragma unroll
    for (int tn = 0; tn < 4; ++tn) {
        f32x4 smA = MFMA_K32(ones8, pbA[0][tn], (f32x4){0.f,0.f,0.f,0.f}, 0,0,0);
        smA = MFMA_K32(ones8, pbA[1][tn], smA, 0,0,0);
        f32x4 smB = MFMA_K32(ones8, pbB[0][tn], (f32x4){0.f,0.f,0.f,0.f}, 0,0,0);
        smB = MFMA_K32(ones8, pbB[1][tn], smB, 0,0,0);
        rsA[tn] = 1.f / smA[0];
        rsB[tn] = 1.f / smB[0];
    }

    // PV with permuted u (P in registers, f16). K=32 x2 per window.
    f32x4 oa0A[4], oa1A[4], oa0B[4], oa1B[4];
    #pragma unroll
    for (int tn = 0; tn < 4; ++tn) {
        oa0A[tn] = (f32x4){0.f,0.f,0.f,0.f}; oa1A[tn] = (f32x4){0.f,0.f,0.f,0.f};
        oa0B[tn] = (f32x4){0.f,0.f,0.f,0.f}; oa1B[tn] = (f32x4){0.f,0.f,0.f,0.f};
    }
    const int d1 = (16 + lr > 23) ? 23 : 16 + lr;     // clamp: garbage rows discarded
    #pragma unroll
    for (int hf = 0; hf < 2; ++hf) {
        const f16x8 av0A = *(const f16x8*)&vtA[vtidx(h*24 + lr, hf*32 + lg*8)];
        const f16x8 av1A = *(const f16x8*)&vtA[vtidx(h*24 + d1, hf*32 + lg*8)];
        const f16x8 av0B = *(const f16x8*)&vtB[vtidx(h*24 + lr, hf*32 + lg*8)];
        const f16x8 av1B = *(const f16x8*)&vtB[vtidx(h*24 + d1, hf*32 + lg*8)];
        #pragma unroll
        for (int tn = 0; tn < 4; ++tn) {
            oa0A[tn] = MFMA_K32(av0A, pbA[hf][tn], oa0A[tn], 0,0,0);
            oa1A[tn] = MFMA_K32(av1A, pbA[hf][tn], oa1A[tn], 0,0,0);
            oa0B[tn] = MFMA_K32(av0B, pbB[hf][tn], oa0B[tn], 0,0,0);
            oa1B[tn] = MFMA_K32(av1B, pbB[hf][tn], oa1B[tn], 0,0,0);
        }
    }

    // ---- preload proj fragments + bias (latency hides under epilogues + B3)
    f16x8 pf[6][3];
    #pragma unroll
    for (int n = 0; n < 6; ++n)
        #pragma unroll
        for (int kk = 0; kk < 3; ++kk)
            pf[n][kk] = *(const f16x8*)(wpL + (n*3 + kk)*512);
    float4 pb4[6];
    #pragma unroll
    for (int n = 0; n < 6; ++n)
        pb4[n] = *(const float4*)(proj_b + 16*n + 4*lg);

    // O epilogues -> qqA/qqB reused as O[t][c] (c = h*24 + d)
    #pragma unroll
    for (int tn = 0; tn < 4; ++tn) {
        const int tt = 16*tn + lr;
        *(f16x4*)&qqA[tt*QS + h*24 + 4*lg] =
            pk4(oa0A[tn][0]*rsA[tn], oa0A[tn][1]*rsA[tn], oa0A[tn][2]*rsA[tn], oa0A[tn][3]*rsA[tn]);
        *(f16x4*)&qqB[tt*QS + h*24 + 4*lg] =
            pk4(oa0B[tn][0]*rsB[tn], oa0B[tn][1]*rsB[tn], oa0B[tn][2]*rsB[tn], oa0B[tn][3]*rsB[tn]);
        if (lg < 2) {                                 // d = 16..23
            *(f16x4*)&qqA[tt*QS + h*24 + 16 + 4*lg] =
                pk4(oa1A[tn][0]*rsA[tn], oa1A[tn][1]*rsA[tn], oa1A[tn][2]*rsA[tn], oa1A[tn][3]*rsA[tn]);
            *(f16x4*)&qqB[tt*QS + h*24 + 16 + 4*lg] =
                pk4(oa1B[tn][0]*rsB[tn], oa1B[tn][1]*rsB[tn], oa1B[tn][2]*rsB[tn], oa1B[tn][3]*rsB[tn]);
        }
    }
    __syncthreads();   // B3: O complete for both windows

    // ---- phase 3: proj. bo reads, then barrier, then o2 writes overlay qq/qk.
    f16x8 boA[3], boB[3];
    #pragma unroll
    for (int kk = 0; kk < 3; ++kk) {
        boA[kk] = *(const f16x8*)&qqA[t*QS + kk*32 + lg*8];
        boB[kk] = *(const f16x8*)&qqB[t*QS + kk*32 + lg*8];
    }
    __syncthreads();   // B4: all O reads done -> o2 may overwrite

    #pragma unroll
    for (int n = 0; n < 6; ++n) {
        f32x4 paA = {0.f,0.f,0.f,0.f}, paB = {0.f,0.f,0.f,0.f};
        #pragma unroll
        for (int kk = 0; kk < 3; ++kk) {
            paA = MFMA_K32(pf[n][kk], boA[kk], paA, 0,0,0);
            paB = MFMA_K32(pf[n][kk], boB[kk], paB, 0,0,0);
        }
        const int c0 = 16*n + 4*lg;                   // lane holds out[t][c0..c0+3]
        float4 ovA = {paA[0]+pb4[n].x, paA[1]+pb4[n].y, paA[2]+pb4[n].z, paA[3]+pb4[n].w};
        float4 ovB = {paB[0]+pb4[n].x, paB[1]+pb4[n].y, paB[2]+pb4[n].z, paB[3]+pb4[n].w};
        *(float4*)&o2A[o2idx(t, c0)] = ovA;
        *(float4*)&o2B[o2idx(t, c0)] = ovB;
    }
    __syncthreads();   // B5: o2 staged

    // ---- coalesced fp32 stores (dense: 384 B contiguous per token)
    #pragma unroll
    for (int it = 0; it < 6; ++it) {
        const int i = it*256 + tid;
        const int tt = i / 24, c4 = (i - tt*24) * 4;
        const size_t po = win_baseA + (size_t)(((tt>>3)<<8) + (tt&7))*96 + c4;
        *(float4*)(out + po)       = *(const float4*)&o2A[o2idx(tt, c4)];
        *(float4*)(out + po + 768) = *(const float4*)&o2B[o2idx(tt, c4)];
    }
}

extern "C" void kernel_launch(void* const* d_in, const int* in_sizes, int n_in,
                              void* d_out, int out_size, void* d_ws, size_t ws_size,
                              hipStream_t stream) {
    const float* x      = (const float*)d_in[0];
    const float* qkv_w  = (const float*)d_in[1];
    const float* qkv_b  = (const float*)d_in[2];
    const float* proj_w = (const float*)d_in[3];
    const float* proj_b = (const float*)d_in[4];
    float* out = (float*)d_out;
    f16* ws = (f16*)d_ws;   // 3456 qw frags | 1152 pw frags | scaled q-bias (96 f32)

    prep_weights<<<dim3(19), dim3(256), 0, stream>>>(qkv_w, proj_w, qkv_b, ws);
    winattn<<<dim3(4096), dim3(256), 0, stream>>>(x, ws, qkv_b, ws + 27648, proj_b, out);
}